// Round 10
// baseline (296.182 us; speedup 1.0000x reference)
//
#include <hip/hip_runtime.h>
#include <hip/hip_cooperative_groups.h>
#include <math.h>

namespace cg = cooperative_groups;

// Problem constants (fixed by the reference)
constexpr int M_ROWS    = 16384;
constexpr int N_PTS     = 16384;
constexpr int MAX_EDGES = 4194304;

constexpr int GD     = 10;                       // cells per dim (cell = R = 0.1)
constexpr int NCELLS = GD * GD * GD;             // 1000
constexpr int NB     = 64;                       // blocks (= binning blocks)
constexpr int TPB    = 256;

static __device__ __forceinline__ int cell_coord(float v) {
    int c = (int)(v * 10.0f);
    return c < 0 ? 0 : (c > GD - 1 ? GD - 1 : c);
}
static __device__ __forceinline__ int cell_id(float x, float y, float z) {
    return (cell_coord(x) * GD + cell_coord(y)) * GD + cell_coord(z);
}

// One cooperative kernel, 64 blocks x 256 threads. Stages separated by
// grid.sync(); no global atomics -> deterministic. R9 lessons baked in:
// per-cell prefixes are WAVE-parallel (shfl scan), never thread-serial and
// never through local arrays (scratch spill).
__global__ void __launch_bounds__(TPB)
fused_kernel(const float* __restrict__ inp, const float* __restrict__ outp,
             int* __restrict__ H,            // [2*NCELLS][NB] counts -> prefixes
             int* __restrict__ cellStart,    // [2][1024]: B at 0, A at 1024
             int* __restrict__ cellTot,      // [2*NCELLS]
             float4* __restrict__ sortedB, int* __restrict__ sortedJ,
             float4* __restrict__ sortedA, int* __restrict__ sortedRow,
             int* __restrict__ totals, int* __restrict__ out_idx,
             int* __restrict__ row_splits, float T) {
    cg::grid_group grid = cg::this_grid();
    __shared__ int hb[NCELLS], ha[NCELLS];
    __shared__ int scB[TPB], scA[TPB];
    __shared__ int sp[TPB];
    int b = blockIdx.x, t = threadIdx.x;
    int tid = b * TPB + t;                       // 0..16383 == point/query index

    // ---- S1: per-block histograms for both sets (transposed H) ----
    for (int i = t; i < NCELLS; i += TPB) { hb[i] = 0; ha[i] = 0; }
    __syncthreads();
    float bx = inp[tid * 3 + 0], by = inp[tid * 3 + 1], bz = inp[tid * 3 + 2];
    float qx = outp[tid * 3 + 0], qy = outp[tid * 3 + 1], qz = outp[tid * 3 + 2];
    int cidB = cell_id(bx, by, bz);
    int cidA = cell_id(qx, qy, qz);
    atomicAdd(&hb[cidB], 1);
    atomicAdd(&ha[cidA], 1);
    __syncthreads();
    for (int i = t; i < NCELLS; i += TPB) {
        H[i * NB + b]            = hb[i];
        H[(NCELLS + i) * NB + b] = ha[i];
    }
    grid.sync();

    // ---- S2: wave-parallel per-cell prefix over blocks ----
    // unit u = (array,cell); lane l holds H[u*64+l]; exclusive shfl scan.
    {
        int wid  = b * (TPB / 64) + (t >> 6);    // 0..255
        int lane = t & 63;
        for (int u = wid; u < 2 * NCELLS; u += NB * (TPB / 64)) {
            int v = H[u * NB + lane];
            int inc = v;
#pragma unroll
            for (int off = 1; off < 64; off <<= 1) {
                int n = __shfl_up(inc, off, 64);
                if (lane >= off) inc += n;
            }
            H[u * NB + lane] = inc - v;          // exclusive intra-cell prefix
            if (lane == 63) cellTot[u] = inc;    // cell total
        }
    }
    grid.sync();

    // ---- S2b: block 0 scans cell totals -> cellStartB/A; others fill -1 ----
    if (b == 0) {
#pragma unroll 1
        for (int g = 0; g < 2; ++g) {
            int* CS = cellStart + g * 1024;
            int base = g * NCELLS;
            int v[4], pre[4];
            int s = 0;
#pragma unroll
            for (int q = 0; q < 4; ++q) {
                int c = t * 4 + q;
                v[q] = (c < NCELLS) ? cellTot[base + c] : 0;
                pre[q] = s; s += v[q];
            }
            sp[t] = s;
            __syncthreads();
            for (int off = 1; off < TPB; off <<= 1) {
                int n = (t >= off) ? sp[t - off] : 0;
                __syncthreads();
                sp[t] += n;
                __syncthreads();
            }
            int ex = (t == 0) ? 0 : sp[t - 1];
#pragma unroll
            for (int q = 0; q < 4; ++q) {
                int c = t * 4 + q;
                if (c <= NCELLS) CS[c] = ex + pre[q];  // c==NCELLS via next thread's pre
            }
            if (t == 255) CS[NCELLS] = sp[255];
            __syncthreads();
        }
    } else {
        // pre-fill ALL of out_idx with -1 (emit overwrites [0,E) later)
        int4* o4 = (int4*)out_idx;
        int n4 = MAX_EDGES / 4;
        for (int i = (b - 1) * TPB + t; i < n4; i += (NB - 1) * TPB)
            o4[i] = make_int4(-1, -1, -1, -1);
    }
    grid.sync();

    // ---- S3: stable scatter (rank = #earlier same-cell points in block) ----
    scB[t] = cidB; scA[t] = cidA;
    __syncthreads();
    int rkB = 0, rkA = 0;
    for (int i = 0; i < TPB - 1; ++i) {          // uniform trip, broadcast reads
        if (i < t) {
            rkB += (scB[i] == cidB);
            rkA += (scA[i] == cidA);
        }
    }
    {
        float sb2 = __fadd_rn(__fadd_rn(__fmul_rn(bx, bx), __fmul_rn(by, by)), __fmul_rn(bz, bz));
        int posB = cellStart[cidB] + H[cidB * NB + b] + rkB;
        sortedB[posB] = make_float4(-2.0f * bx, -2.0f * by, -2.0f * bz, sb2);
        sortedJ[posB] = tid;
        float sa2 = __fadd_rn(__fadd_rn(__fmul_rn(qx, qx), __fmul_rn(qy, qy)), __fmul_rn(qz, qz));
        int posA = cellStart[1024 + cidA] + H[(NCELLS + cidA) * NB + b] + rkA;
        sortedA[posA] = make_float4(qx, qy, qz, __fsub_rn(T, sa2));
        sortedRow[posA] = tid;
    }
    grid.sync();

    // ---- S4: count — one thread per sorted query, all 27 neighbor cells ----
    {
        float4 a = sortedA[tid];
        int ccx = cell_coord(a.x), ccy = cell_coord(a.y), ccz = cell_coord(a.z);
        int sum = 0;
#pragma unroll 1
        for (int k = 0; k < 27; ++k) {
            int cx = ccx + (k / 9) - 1;
            int cy = ccy + ((k / 3) % 3) - 1;
            int cz = ccz + (k % 3) - 1;
            if (((unsigned)cx < GD) & ((unsigned)cy < GD) & ((unsigned)cz < GD)) {
                int cid = (cx * GD + cy) * GD + cz;
                int s = cellStart[cid], e = cellStart[cid + 1];
                for (int p = s; p < e; ++p) {
                    float4 q = sortedB[p];
                    float v = __fmaf_rn(a.x, q.x, __fmaf_rn(a.y, q.y, __fmaf_rn(a.z, q.z, q.w)));
                    sum += (v <= a.w);
                }
            }
        }
        totals[sortedRow[tid]] = sum;
    }
    grid.sync();

    // ---- S5: block 0 — global exclusive scan of totals -> row_splits ----
    if (b == 0) {
        const int4* t4 = (const int4*)totals;
        int s = 0;
#pragma unroll 1
        for (int i = 0; i < 16; ++i) {
            int4 v = t4[t * 16 + i];
            s += v.x + v.y + v.z + v.w;
        }
        sp[t] = s;
        __syncthreads();
        for (int off = 1; off < TPB; off <<= 1) {
            int n = (t >= off) ? sp[t - off] : 0;
            __syncthreads();
            sp[t] += n;
            __syncthreads();
        }
        int cur = (t == 0) ? 0 : sp[t - 1];
#pragma unroll 1
        for (int i = 0; i < 16; ++i) {
            int4 v = t4[t * 16 + i];
            row_splits[t * 64 + i * 4 + 0] = cur; cur += v.x;
            row_splits[t * 64 + i * 4 + 1] = cur; cur += v.y;
            row_splits[t * 64 + i * 4 + 2] = cur; cur += v.z;
            row_splits[t * 64 + i * 4 + 3] = cur; cur += v.w;
        }
        if (t == 255) row_splits[M_ROWS] = sp[255];
    }
    grid.sync();

    // ---- S6: emit — one thread per sorted query, stream its whole row ----
    {
        float4 a = sortedA[tid];
        int ccx = cell_coord(a.x), ccy = cell_coord(a.y), ccz = cell_coord(a.z);
        int cur = row_splits[sortedRow[tid]];
#pragma unroll 1
        for (int k = 0; k < 27; ++k) {
            int cx = ccx + (k / 9) - 1;
            int cy = ccy + ((k / 3) % 3) - 1;
            int cz = ccz + (k % 3) - 1;
            if (((unsigned)cx < GD) & ((unsigned)cy < GD) & ((unsigned)cz < GD)) {
                int cid = (cx * GD + cy) * GD + cz;
                int s = cellStart[cid], e = cellStart[cid + 1];
                for (int p = s; p < e; ++p) {
                    float4 q = sortedB[p];
                    float v = __fmaf_rn(a.x, q.x, __fmaf_rn(a.y, q.y, __fmaf_rn(a.z, q.z, q.w)));
                    if (v <= a.w) out_idx[cur++] = sortedJ[p];
                }
            }
        }
    }
}

extern "C" void kernel_launch(void* const* d_in, const int* in_sizes, int n_in,
                              void* d_out, int out_size, void* d_ws, size_t ws_size,
                              hipStream_t stream) {
    const float* inp  = (const float*)d_in[0];   // inp_positions [16384,3]
    const float* outp = (const float*)d_in[1];   // out_positions [16384,3]
    int* out_idx    = (int*)d_out;               // [MAX_EDGES]
    int* row_splits = out_idx + MAX_EDGES;       // [M+1]

    char* ws = (char*)d_ws;
    size_t off = 0;
    float4* sortedB = (float4*)(ws + off); off += (size_t)N_PTS * 16;         // 256 KB
    float4* sortedA = (float4*)(ws + off); off += (size_t)M_ROWS * 16;        // 256 KB
    int* H          = (int*)(ws + off);    off += (size_t)2 * NCELLS * NB * 4;// 512 KB
    int* cellStart  = (int*)(ws + off);    off += 2048 * 4;
    int* cellTot    = (int*)(ws + off);    off += 2048 * 4;
    int* sortedJ    = (int*)(ws + off);    off += (size_t)N_PTS * 4;          // 64 KB
    int* sortedRow  = (int*)(ws + off);    off += (size_t)M_ROWS * 4;         // 64 KB
    int* totals     = (int*)(ws + off);    off += (size_t)M_ROWS * 4;         // 64 KB
    if (off > ws_size) return;  // ~1.2 MB; ws is 256 MB

    // T = largest fp32 strictly below (0.1f + 2^-28)^2: d2<=T <=> sqrt(max(d2,0))<=0.1f
    double md = (double)0.1f + ldexp(1.0, -28);
    double m2 = md * md;
    float  T  = (float)m2;
    if ((double)T >= m2) T = nextafterf(T, 0.0f);

    void* kargs[] = {
        (void*)&inp, (void*)&outp, (void*)&H, (void*)&cellStart, (void*)&cellTot,
        (void*)&sortedB, (void*)&sortedJ, (void*)&sortedA, (void*)&sortedRow,
        (void*)&totals, (void*)&out_idx, (void*)&row_splits, (void*)&T
    };
    hipLaunchCooperativeKernel((const void*)fused_kernel, dim3(NB), dim3(TPB),
                               kargs, 0, stream);
}